// Round 1
// baseline (1016.988 us; speedup 1.0000x reference)
//
#include <hip/hip_runtime.h>
#include <hip/hip_bf16.h>

#define TOKENS 16384
#define MDIM   1024
#define HDIM   4096
#define HHALF  2048
#define NEXP   8
#define CAP    2048

typedef __attribute__((ext_vector_type(8))) short bf16x8;  // 8 bf16 = 4 VGPR
typedef __attribute__((ext_vector_type(4))) float f32x4;

__device__ __forceinline__ short f2bf(float x) {
  // RNE float->bf16 (values are finite; no NaN path needed)
  unsigned u = __float_as_uint(x);
  unsigned r = (u + 0x7fffu + ((u >> 16) & 1u)) >> 16;
  return (short)r;
}

__device__ __forceinline__ float gelu_f(float x) {
  // jax.nn.gelu approximate=True: 0.5x(1+tanh(sqrt(2/pi)(x+0.044715x^3)))
  float u = 1.5957691216057308f * (x + 0.044715f * x * x * x);  // 2*y
  float e = __expf(u);
  return x * (1.f - 1.f / (e + 1.f));  // x * e/(e+1), inf-safe form
}

// ---------------- gating: logits -> softmax -> argmax ----------------
__global__ __launch_bounds__(256) void gating_kernel(
    const float* __restrict__ x, const float* __restrict__ wg,
    int* __restrict__ idx, float* __restrict__ gate,
    float* __restrict__ mepart) {
  __shared__ float me_s[NEXP];
  int tid = threadIdx.x, wid = tid >> 6, lane = tid & 63;
  if (tid < NEXP) me_s[tid] = 0.f;
  __syncthreads();
  int t = blockIdx.x * 4 + wid;
  float acc[NEXP];
#pragma unroll
  for (int e = 0; e < NEXP; e++) acc[e] = 0.f;
  const float4* xr = (const float4*)(x + (size_t)t * MDIM);
#pragma unroll
  for (int j = 0; j < 4; j++) {
    float4 xv = xr[lane * 4 + j];
    int base = lane * 16 + j * 4;
    const float* xp = &xv.x;
#pragma unroll
    for (int i = 0; i < 4; i++) {
      float xi = xp[i];
      const float4* wr = (const float4*)(wg + (size_t)(base + i) * NEXP);
      float4 w0 = wr[0], w1 = wr[1];
      acc[0] += xi * w0.x; acc[1] += xi * w0.y; acc[2] += xi * w0.z; acc[3] += xi * w0.w;
      acc[4] += xi * w1.x; acc[5] += xi * w1.y; acc[6] += xi * w1.z; acc[7] += xi * w1.w;
    }
  }
#pragma unroll
  for (int off = 32; off > 0; off >>= 1)
#pragma unroll
    for (int e = 0; e < NEXP; e++) acc[e] += __shfl_xor(acc[e], off, 64);
  if (lane == 0) {
    float mx = acc[0]; int ai = 0;
#pragma unroll
    for (int e = 1; e < NEXP; e++) if (acc[e] > mx) { mx = acc[e]; ai = e; }  // first-max, matches np.argmax
    float ex[NEXP]; float se = 0.f;
#pragma unroll
    for (int e = 0; e < NEXP; e++) { ex[e] = __expf(acc[e] - mx); se += ex[e]; }
    float inv = 1.f / se;
#pragma unroll
    for (int e = 0; e < NEXP; e++) atomicAdd(&me_s[e], ex[e] * inv);
    idx[t] = ai;
    gate[t] = inv;  // ex[ai]==1 -> gate value = 1/se
  }
  __syncthreads();
  if (tid < NEXP) mepart[blockIdx.x * NEXP + tid] = me_s[tid];
}

// ---------------- single-block ordered scan: queue positions ----------------
__global__ __launch_bounds__(1024) void scan_kernel(
    const int* __restrict__ idx, float* __restrict__ gate,
    int* __restrict__ s2t, int* __restrict__ counts) {
  __shared__ int wcnt[16][NEXP];
  __shared__ int base[NEXP];
  int tid = threadIdx.x, wid = tid >> 6, lane = tid & 63;
  if (tid < NEXP) base[tid] = 0;
  __syncthreads();
  for (int chunk = 0; chunk < TOKENS; chunk += 1024) {
    int i = chunk + tid;
    int e = idx[i];
    int pre = 0;
#pragma unroll
    for (int e2 = 0; e2 < NEXP; e2++) {
      unsigned long long b = __ballot(e == e2);
      if (e2 == e) pre = __popcll(b & ((1ull << lane) - 1ull));
      if (lane == 0) wcnt[wid][e2] = __popcll(b);
    }
    __syncthreads();
    int off = base[e];
    for (int w = 0; w < wid; w++) off += wcnt[w][e];
    int loc = off + pre;
    if (loc < CAP) s2t[e * CAP + loc] = i;
    else           gate[i] = 0.f;   // capacity drop
    __syncthreads();
    if (tid < NEXP) {
      int tsum = 0;
#pragma unroll
      for (int w = 0; w < 16; w++) tsum += wcnt[w][tid];
      base[tid] += tsum;
    }
    __syncthreads();
  }
  if (tid < NEXP) counts[tid] = base[tid];  // pre-drop exp_counts
}

// ---------------- l_aux + exp_counts tail ----------------
__global__ __launch_bounds__(256) void finalize_kernel(
    const float* __restrict__ mepart, const int* __restrict__ counts,
    float* __restrict__ out_tail, int nblocks) {
  __shared__ float red[256];
  __shared__ float me[NEXP];
  int tid = threadIdx.x;
  float s = 0.f;
  int e = tid & 7;
  for (int r = tid >> 3; r < nblocks; r += 32) s += mepart[r * NEXP + e];
  red[tid] = s;
  __syncthreads();
  if (tid < NEXP) {
    float tsum = 0.f;
    for (int i = tid; i < 256; i += 8) tsum += red[i];
    me[tid] = tsum;
  }
  __syncthreads();
  if (tid == 0) {
    float la = 0.f;
    for (int k = 0; k < NEXP; k++)
      la += (me[k] / (float)TOKENS) * ((float)counts[k] / (float)TOKENS);
    out_tail[0] = la * (float)NEXP;
  }
  if (tid < NEXP) out_tail[1 + tid] = (float)counts[tid];
}

// ---------------- fp32 [E][R][C] -> bf16 [E][C][R] ----------------
__global__ __launch_bounds__(256) void transpose_cvt_kernel(
    const float* __restrict__ in, short* __restrict__ out, int R, int Cc) {
  __shared__ float tile[32][33];
  int e = blockIdx.z;
  const float* in_e = in + (size_t)e * R * Cc;
  short* out_e = out + (size_t)e * R * Cc;
  int r0 = blockIdx.y * 32, c0 = blockIdx.x * 32;
  int tx = threadIdx.x & 31, ty = threadIdx.x >> 5;  // ty 0..7
#pragma unroll
  for (int i = 0; i < 4; i++)
    tile[ty + i * 8][tx] = in_e[(size_t)(r0 + ty + i * 8) * Cc + c0 + tx];
  __syncthreads();
#pragma unroll
  for (int i = 0; i < 4; i++)
    out_e[(size_t)(c0 + ty + i * 8) * R + r0 + tx] = f2bf(tile[tx][ty + i * 8]);
}

// ---------------- gather tokens into per-expert bf16 A [E][CAP][M] ----------------
__global__ __launch_bounds__(256) void dispatch_kernel(
    const float* __restrict__ x, const int* __restrict__ s2t,
    short* __restrict__ A) {
  int slot = blockIdx.x;
  int token = s2t[slot];
  short4 v;
  if (token >= 0) {
    float4 xv = ((const float4*)(x + (size_t)token * MDIM))[threadIdx.x];
    v.x = f2bf(xv.x); v.y = f2bf(xv.y); v.z = f2bf(xv.z); v.w = f2bf(xv.w);
  } else {
    v.x = 0; v.y = 0; v.z = 0; v.w = 0;
  }
  ((short4*)(A + (size_t)slot * MDIM))[threadIdx.x] = v;
}

// ---------------- m97-style staging: 128 rows x 64 shorts, 16B-chunk XOR swizzle ----------------
__device__ __forceinline__ void stage_tile(const short* __restrict__ g0, int ldk,
                                           short* lds, int tid) {
  int w = tid >> 6, lane = tid & 63;
#pragma unroll
  for (int i = 0; i < 4; i++) {
    int rbase = w * 32 + i * 8;
    int r = rbase + (lane >> 3);
    int c = (lane & 7) ^ (r & 7);                 // swizzle on the global gather side
    const short* g = g0 + (size_t)r * ldk + c * 8;
    short* l = lds + rbase * 64;                  // wave-uniform LDS base; HW: +lane*16B
    __builtin_amdgcn_global_load_lds((const __attribute__((address_space(1))) void*)g,
                                     (__attribute__((address_space(3))) void*)l,
                                     16, 0, 0);
  }
}

// ---------------- GEMM1: A[E,CAP,M] @ W1t[E,H,M]^T -> gelu -> Hh bf16 [E,CAP,HHALF] ----------------
__global__ __launch_bounds__(256) void gemm1_kernel(
    const short* __restrict__ A, const short* __restrict__ Bt,
    const float* __restrict__ b1, short* __restrict__ Hh, int p) {
  __shared__ __align__(16) short ldsA[128 * 64];
  __shared__ __align__(16) short ldsB[128 * 64];
  int e = blockIdx.z, bm = blockIdx.y, bn = blockIdx.x;
  const short* Ae = A  + ((size_t)e * CAP  + (size_t)bm * 128) * MDIM;
  const short* Be = Bt + ((size_t)e * HDIM + (size_t)(p * HHALF + bn * 128)) * MDIM;
  int tid = threadIdx.x, lane = tid & 63, w = tid >> 6;
  int wr = (w >> 1) * 64, wc = (w & 1) * 64;
  f32x4 acc[4][4];
  f32x4 zero = {0.f, 0.f, 0.f, 0.f};
#pragma unroll
  for (int a = 0; a < 4; a++)
#pragma unroll
    for (int b = 0; b < 4; b++) acc[a][b] = zero;
  for (int kt = 0; kt < MDIM; kt += 64) {
    __syncthreads();
    stage_tile(Ae + kt, MDIM, ldsA, tid);
    stage_tile(Be + kt, MDIM, ldsB, tid);
    __syncthreads();
#pragma unroll
    for (int kk = 0; kk < 2; kk++) {
      bf16x8 af[4], bfr[4];
#pragma unroll
      for (int rt = 0; rt < 4; rt++) {
        int r = wr + rt * 16 + (lane & 15);
        int c = (kk * 4 + (lane >> 4)) ^ (r & 7);
        af[rt] = *(const bf16x8*)(ldsA + r * 64 + c * 8);
      }
#pragma unroll
      for (int ct = 0; ct < 4; ct++) {
        int r = wc + ct * 16 + (lane & 15);
        int c = (kk * 4 + (lane >> 4)) ^ (r & 7);
        bfr[ct] = *(const bf16x8*)(ldsB + r * 64 + c * 8);
      }
#pragma unroll
      for (int rt = 0; rt < 4; rt++)
#pragma unroll
        for (int ct = 0; ct < 4; ct++)
          acc[rt][ct] = __builtin_amdgcn_mfma_f32_16x16x32_bf16(af[rt], bfr[ct], acc[rt][ct], 0, 0, 0);
    }
  }
  int q = lane >> 4, ln = lane & 15;
#pragma unroll
  for (int ct = 0; ct < 4; ct++) {
    int coll = bn * 128 + wc + ct * 16 + ln;            // col within half
    float bias = b1[e * HDIM + p * HHALF + coll];
#pragma unroll
    for (int rt = 0; rt < 4; rt++) {
#pragma unroll
      for (int rg = 0; rg < 4; rg++) {
        int row = bm * 128 + wr + rt * 16 + q * 4 + rg;
        float v = acc[rt][ct][rg] + bias;
        Hh[((size_t)e * CAP + row) * HHALF + coll] = f2bf(gelu_f(v));
      }
    }
  }
}

// ---------------- GEMM2 + fused combine: Hh @ W2t^T, scatter rows * gate ----------------
__global__ __launch_bounds__(256) void gemm2_kernel(
    const short* __restrict__ Hh, const short* __restrict__ W2t,
    const float* __restrict__ b2, const int* __restrict__ s2t,
    const float* __restrict__ gate, float* __restrict__ out, int p) {
  __shared__ __align__(16) short ldsA[128 * 64];
  __shared__ __align__(16) short ldsB[128 * 64];
  int e = blockIdx.z, bm = blockIdx.y, bn = blockIdx.x;
  const short* Ae = Hh + ((size_t)e * CAP + (size_t)bm * 128) * HHALF;
  const short* Be = W2t + ((size_t)e * MDIM + (size_t)bn * 128) * HDIM + (size_t)p * HHALF;
  int tid = threadIdx.x, lane = tid & 63, w = tid >> 6;
  int wr = (w >> 1) * 64, wc = (w & 1) * 64;
  f32x4 acc[4][4];
  f32x4 zero = {0.f, 0.f, 0.f, 0.f};
#pragma unroll
  for (int a = 0; a < 4; a++)
#pragma unroll
    for (int b = 0; b < 4; b++) acc[a][b] = zero;
  for (int kt = 0; kt < HHALF; kt += 64) {
    __syncthreads();
    stage_tile(Ae + kt, HHALF, ldsA, tid);
    stage_tile(Be + kt, HDIM, ldsB, tid);
    __syncthreads();
#pragma unroll
    for (int kk = 0; kk < 2; kk++) {
      bf16x8 af[4], bfr[4];
#pragma unroll
      for (int rt = 0; rt < 4; rt++) {
        int r = wr + rt * 16 + (lane & 15);
        int c = (kk * 4 + (lane >> 4)) ^ (r & 7);
        af[rt] = *(const bf16x8*)(ldsA + r * 64 + c * 8);
      }
#pragma unroll
      for (int ct = 0; ct < 4; ct++) {
        int r = wc + ct * 16 + (lane & 15);
        int c = (kk * 4 + (lane >> 4)) ^ (r & 7);
        bfr[ct] = *(const bf16x8*)(ldsB + r * 64 + c * 8);
      }
#pragma unroll
      for (int rt = 0; rt < 4; rt++)
#pragma unroll
        for (int ct = 0; ct < 4; ct++)
          acc[rt][ct] = __builtin_amdgcn_mfma_f32_16x16x32_bf16(af[rt], bfr[ct], acc[rt][ct], 0, 0, 0);
    }
  }
  int q = lane >> 4, ln = lane & 15;
#pragma unroll
  for (int rt = 0; rt < 4; rt++) {
#pragma unroll
    for (int rg = 0; rg < 4; rg++) {
      int row = bm * 128 + wr + rt * 16 + q * 4 + rg;
      int token = s2t[e * CAP + row];
      if (token < 0) continue;                   // empty slot
      float g = gate[token];
#pragma unroll
      for (int ct = 0; ct < 4; ct++) {
        int col = bn * 128 + wc + ct * 16 + ln;
        float v = acc[rt][ct][rg];
        size_t o = (size_t)token * MDIM + col;
        if (p == 0) out[o] = (v + b2[e * MDIM + col]) * g;
        else        out[o] += v * g;
      }
    }
  }
}

// ---------------- zero rows of dropped tokens ----------------
__global__ __launch_bounds__(256) void zerodrop_kernel(
    const float* __restrict__ gate, float* __restrict__ out) {
  int t = blockIdx.x;
  if (gate[t] != 0.f) return;
  float4 z = {0.f, 0.f, 0.f, 0.f};
  ((float4*)(out + (size_t)t * MDIM))[threadIdx.x] = z;
}

extern "C" void kernel_launch(void* const* d_in, const int* in_sizes, int n_in,
                              void* d_out, int out_size, void* d_ws, size_t ws_size,
                              hipStream_t stream) {
  const float* x  = (const float*)d_in[0];
  const float* wg = (const float*)d_in[1];
  const float* w1 = (const float*)d_in[2];
  const float* b1 = (const float*)d_in[3];
  const float* w2 = (const float*)d_in[4];
  const float* b2 = (const float*)d_in[5];
  float* out = (float*)d_out;

  char* ws = (char*)d_ws;
  size_t off = 0;
  auto alloc = [&](size_t n) { char* ptr = ws + off; off += (n + 255) & ~(size_t)255; return ptr; };
  short* W1t  = (short*)alloc((size_t)NEXP * MDIM * HDIM * 2);   // 67 MB  [E][H][M]
  short* W2t  = (short*)alloc((size_t)NEXP * MDIM * HDIM * 2);   // 67 MB  [E][M][H]
  short* Adis = (short*)alloc((size_t)NEXP * CAP * MDIM * 2);    // 33.5 MB
  short* Hh   = (short*)alloc((size_t)NEXP * CAP * HHALF * 2);   // 67 MB (half of H)
  int*   idx  = (int*)  alloc(TOKENS * 4);
  float* gate = (float*)alloc(TOKENS * 4);
  int*   s2t  = (int*)  alloc(NEXP * CAP * 4);
  float* mep  = (float*)alloc((TOKENS / 4) * NEXP * 4);
  int*   cnts = (int*)  alloc(NEXP * 4);
  if (ws_size < off) return;  // clean failure signal if ws too small

  hipMemsetAsync(s2t, 0xFF, NEXP * CAP * 4, stream);  // -1 sentinels

  gating_kernel<<<TOKENS / 4, 256, 0, stream>>>(x, wg, idx, gate, mep);
  scan_kernel<<<1, 1024, 0, stream>>>(idx, gate, s2t, cnts);
  finalize_kernel<<<1, 256, 0, stream>>>(mep, cnts, out + (size_t)TOKENS * MDIM, TOKENS / 4);
  transpose_cvt_kernel<<<dim3(HDIM / 32, MDIM / 32, NEXP), 256, 0, stream>>>(w1, W1t, MDIM, HDIM);
  transpose_cvt_kernel<<<dim3(MDIM / 32, HDIM / 32, NEXP), 256, 0, stream>>>(w2, W2t, HDIM, MDIM);
  dispatch_kernel<<<NEXP * CAP, 256, 0, stream>>>(x, s2t, Adis);
  for (int p = 0; p < 2; p++) {
    gemm1_kernel<<<dim3(HHALF / 128, CAP / 128, NEXP), 256, 0, stream>>>(Adis, W1t, b1, Hh, p);
    gemm2_kernel<<<dim3(MDIM / 128, CAP / 128, NEXP), 256, 0, stream>>>(Hh, W2t, b2, s2t, gate, out, p);
  }
  zerodrop_kernel<<<TOKENS, 256, 0, stream>>>(gate, out);
}

// Round 2
// 933.582 us; speedup vs baseline: 1.0893x; 1.0893x over previous
//
#include <hip/hip_runtime.h>
#include <hip/hip_bf16.h>

#define TOKENS 16384
#define MDIM   1024
#define HDIM   4096
#define NEXP   8
#define EGRP   4          // experts per GEMM group (2 groups)
#define CAP    2048

typedef __attribute__((ext_vector_type(8))) short bf16x8;  // 8 bf16 = 4 VGPR
typedef __attribute__((ext_vector_type(4))) float f32x4;

__device__ __forceinline__ short f2bf(float x) {
  unsigned u = __float_as_uint(x);
  unsigned r = (u + 0x7fffu + ((u >> 16) & 1u)) >> 16;
  return (short)r;
}

__device__ __forceinline__ float gelu_f(float x) {
  // jax.nn.gelu approximate=True
  float u = 1.5957691216057308f * (x + 0.044715f * x * x * x);
  float e = __expf(u);
  return x * (1.f - 1.f / (e + 1.f));
}

// ---------------- gating: logits -> softmax -> argmax; also emit bf16 x ----------------
__global__ __launch_bounds__(256) void gating_kernel(
    const float* __restrict__ x, const float* __restrict__ wg,
    int* __restrict__ idx, float* __restrict__ gate,
    float* __restrict__ mepart, short* __restrict__ xb) {
  __shared__ float me_s[NEXP];
  int tid = threadIdx.x, wid = tid >> 6, lane = tid & 63;
  if (tid < NEXP) me_s[tid] = 0.f;
  __syncthreads();
  int t = blockIdx.x * 4 + wid;
  float acc[NEXP];
#pragma unroll
  for (int e = 0; e < NEXP; e++) acc[e] = 0.f;
  const float4* xr = (const float4*)(x + (size_t)t * MDIM);
  short* xbr = xb + (size_t)t * MDIM + lane * 16;
#pragma unroll
  for (int j = 0; j < 4; j++) {
    float4 xv = xr[lane * 4 + j];
    short4 bv; bv.x = f2bf(xv.x); bv.y = f2bf(xv.y); bv.z = f2bf(xv.z); bv.w = f2bf(xv.w);
    ((short4*)(xbr))[j] = bv;
    int base = lane * 16 + j * 4;
    const float* xp = &xv.x;
#pragma unroll
    for (int i = 0; i < 4; i++) {
      float xi = xp[i];
      const float4* wr = (const float4*)(wg + (size_t)(base + i) * NEXP);
      float4 w0 = wr[0], w1 = wr[1];
      acc[0] += xi * w0.x; acc[1] += xi * w0.y; acc[2] += xi * w0.z; acc[3] += xi * w0.w;
      acc[4] += xi * w1.x; acc[5] += xi * w1.y; acc[6] += xi * w1.z; acc[7] += xi * w1.w;
    }
  }
#pragma unroll
  for (int off = 32; off > 0; off >>= 1)
#pragma unroll
    for (int e = 0; e < NEXP; e++) acc[e] += __shfl_xor(acc[e], off, 64);
  if (lane == 0) {
    float mx = acc[0]; int ai = 0;
#pragma unroll
    for (int e = 1; e < NEXP; e++) if (acc[e] > mx) { mx = acc[e]; ai = e; }
    float ex[NEXP]; float se = 0.f;
#pragma unroll
    for (int e = 0; e < NEXP; e++) { ex[e] = __expf(acc[e] - mx); se += ex[e]; }
    float inv = 1.f / se;
#pragma unroll
    for (int e = 0; e < NEXP; e++) atomicAdd(&me_s[e], ex[e] * inv);
    idx[t] = ai;
    gate[t] = inv;
  }
  __syncthreads();
  if (tid < NEXP) mepart[blockIdx.x * NEXP + tid] = me_s[tid];
}

// ---------------- single-block ordered scan: queue positions ----------------
__global__ __launch_bounds__(1024) void scan_kernel(
    const int* __restrict__ idx, float* __restrict__ gate,
    int* __restrict__ s2t, int* __restrict__ counts) {
  __shared__ int wcnt[16][NEXP];
  __shared__ int base[NEXP];
  int tid = threadIdx.x, wid = tid >> 6, lane = tid & 63;
  if (tid < NEXP) base[tid] = 0;
  __syncthreads();
  for (int chunk = 0; chunk < TOKENS; chunk += 1024) {
    int i = chunk + tid;
    int e = idx[i];
    int pre = 0;
#pragma unroll
    for (int e2 = 0; e2 < NEXP; e2++) {
      unsigned long long b = __ballot(e == e2);
      if (e2 == e) pre = __popcll(b & ((1ull << lane) - 1ull));
      if (lane == 0) wcnt[wid][e2] = __popcll(b);
    }
    __syncthreads();
    int off = base[e];
    for (int w = 0; w < wid; w++) off += wcnt[w][e];
    int loc = off + pre;
    if (loc < CAP) s2t[e * CAP + loc] = i;
    else           gate[i] = 0.f;
    __syncthreads();
    if (tid < NEXP) {
      int tsum = 0;
#pragma unroll
      for (int w = 0; w < 16; w++) tsum += wcnt[w][tid];
      base[tid] += tsum;
    }
    __syncthreads();
  }
  if (tid < NEXP) counts[tid] = base[tid];
}

// ---------------- l_aux + exp_counts tail ----------------
__global__ __launch_bounds__(256) void finalize_kernel(
    const float* __restrict__ mepart, const int* __restrict__ counts,
    float* __restrict__ out_tail, int nblocks) {
  __shared__ float red[256];
  __shared__ float me[NEXP];
  int tid = threadIdx.x;
  float s = 0.f;
  int e = tid & 7;
  for (int r = tid >> 3; r < nblocks; r += 32) s += mepart[r * NEXP + e];
  red[tid] = s;
  __syncthreads();
  if (tid < NEXP) {
    float tsum = 0.f;
    for (int i = tid; i < 256; i += 8) tsum += red[i];
    me[tid] = tsum;
  }
  __syncthreads();
  if (tid == 0) {
    float la = 0.f;
    for (int k = 0; k < NEXP; k++)
      la += (me[k] / (float)TOKENS) * ((float)counts[k] / (float)TOKENS);
    out_tail[0] = la * (float)NEXP;
  }
  if (tid < NEXP) out_tail[1 + tid] = (float)counts[tid];
}

// ---------------- fp32 [E][R][C] -> bf16 [E][C][R] ----------------
__global__ __launch_bounds__(256) void transpose_cvt_kernel(
    const float* __restrict__ in, short* __restrict__ out, int R, int Cc) {
  __shared__ float tile[32][33];
  int e = blockIdx.z;
  const float* in_e = in + (size_t)e * R * Cc;
  short* out_e = out + (size_t)e * R * Cc;
  int r0 = blockIdx.y * 32, c0 = blockIdx.x * 32;
  int tx = threadIdx.x & 31, ty = threadIdx.x >> 5;
#pragma unroll
  for (int i = 0; i < 4; i++)
    tile[ty + i * 8][tx] = in_e[(size_t)(r0 + ty + i * 8) * Cc + c0 + tx];
  __syncthreads();
#pragma unroll
  for (int i = 0; i < 4; i++)
    out_e[(size_t)(c0 + ty + i * 8) * R + r0 + tx] = f2bf(tile[tx][ty + i * 8]);
}

// ---------------- m97-style staging for regular (non-gather) operand ----------------
__device__ __forceinline__ void stage_tile(const short* __restrict__ g0, int ldk,
                                           short* lds, int tid) {
  int w = tid >> 6, lane = tid & 63;
#pragma unroll
  for (int i = 0; i < 4; i++) {
    int rbase = w * 32 + i * 8;
    int r = rbase + (lane >> 3);
    int c = (lane & 7) ^ (r & 7);
    const short* g = g0 + (size_t)r * ldk + c * 8;
    short* l = lds + rbase * 64;
    __builtin_amdgcn_global_load_lds((const __attribute__((address_space(1))) void*)g,
                                     (__attribute__((address_space(3))) void*)l,
                                     16, 0, 0);
  }
}

// ---------------- GEMM1 (gathered A): xb rows via s2t @ W1t^T -> gelu -> Hh ----------------
__global__ __launch_bounds__(256) void gemm1_kernel(
    const short* __restrict__ xb, const int* __restrict__ s2t,
    const short* __restrict__ W1t, const float* __restrict__ b1,
    short* __restrict__ Hh, const short* __restrict__ zrow, int eg) {
  __shared__ __align__(16) short ldsA[128 * 64];
  __shared__ __align__(16) short ldsB[128 * 64];
  int bz = blockIdx.z, bm = blockIdx.y, bn = blockIdx.x;
  int e_abs = eg + bz;
  const short* Be = W1t + ((size_t)e_abs * HDIM + (size_t)bn * 128) * MDIM;
  int tid = threadIdx.x, lane = tid & 63, w = tid >> 6;
  // per-thread gathered row pointers (constant across K-loop)
  const short* aptr[4];
#pragma unroll
  for (int i = 0; i < 4; i++) {
    int rb = w * 32 + i * 8;
    int r = rb + (lane >> 3);
    int tok = s2t[e_abs * CAP + bm * 128 + r];
    const short* basep = (tok >= 0) ? (xb + (size_t)tok * MDIM) : zrow;
    aptr[i] = basep + (((lane & 7) ^ (r & 7)) * 8);
  }
  int wr = (w >> 1) * 64, wc = (w & 1) * 64;
  f32x4 acc[4][4];
  f32x4 zero = {0.f, 0.f, 0.f, 0.f};
#pragma unroll
  for (int a = 0; a < 4; a++)
#pragma unroll
    for (int b = 0; b < 4; b++) acc[a][b] = zero;
  for (int kt = 0; kt < MDIM; kt += 64) {
    __syncthreads();
#pragma unroll
    for (int i = 0; i < 4; i++) {
      short* l = ldsA + (w * 32 + i * 8) * 64;
      __builtin_amdgcn_global_load_lds((const __attribute__((address_space(1))) void*)(aptr[i] + kt),
                                       (__attribute__((address_space(3))) void*)l,
                                       16, 0, 0);
    }
    stage_tile(Be + kt, MDIM, ldsB, tid);
    __syncthreads();
#pragma unroll
    for (int kk = 0; kk < 2; kk++) {
      bf16x8 af[4], bfr[4];
#pragma unroll
      for (int rt = 0; rt < 4; rt++) {
        int r = wr + rt * 16 + (lane & 15);
        int c = (kk * 4 + (lane >> 4)) ^ (r & 7);
        af[rt] = *(const bf16x8*)(ldsA + r * 64 + c * 8);
      }
#pragma unroll
      for (int ct = 0; ct < 4; ct++) {
        int r = wc + ct * 16 + (lane & 15);
        int c = (kk * 4 + (lane >> 4)) ^ (r & 7);
        bfr[ct] = *(const bf16x8*)(ldsB + r * 64 + c * 8);
      }
#pragma unroll
      for (int rt = 0; rt < 4; rt++)
#pragma unroll
        for (int ct = 0; ct < 4; ct++)
          acc[rt][ct] = __builtin_amdgcn_mfma_f32_16x16x32_bf16(af[rt], bfr[ct], acc[rt][ct], 0, 0, 0);
    }
  }
  int q = lane >> 4, ln = lane & 15;
#pragma unroll
  for (int ct = 0; ct < 4; ct++) {
    int col = bn * 128 + wc + ct * 16 + ln;
    float bias = b1[e_abs * HDIM + col];
#pragma unroll
    for (int rt = 0; rt < 4; rt++) {
#pragma unroll
      for (int rg = 0; rg < 4; rg++) {
        int row = bm * 128 + wr + rt * 16 + q * 4 + rg;
        float v = acc[rt][ct][rg] + bias;
        Hh[((size_t)bz * CAP + row) * HDIM + col] = f2bf(gelu_f(v));
      }
    }
  }
}

// ---------------- GEMM2 (full K=H) + fused combine, write-once ----------------
__global__ __launch_bounds__(256) void gemm2_kernel(
    const short* __restrict__ Hh, const short* __restrict__ W2t,
    const float* __restrict__ b2, const int* __restrict__ s2t,
    const float* __restrict__ gate, float* __restrict__ out, int eg) {
  __shared__ __align__(16) short ldsA[128 * 64];
  __shared__ __align__(16) short ldsB[128 * 64];
  int bz = blockIdx.z, bm = blockIdx.y, bn = blockIdx.x;
  int e_abs = eg + bz;
  const short* Ae = Hh + ((size_t)bz * CAP + (size_t)bm * 128) * HDIM;
  const short* Be = W2t + ((size_t)e_abs * MDIM + (size_t)bn * 128) * HDIM;
  int tid = threadIdx.x, lane = tid & 63, w = tid >> 6;
  int wr = (w >> 1) * 64, wc = (w & 1) * 64;
  f32x4 acc[4][4];
  f32x4 zero = {0.f, 0.f, 0.f, 0.f};
#pragma unroll
  for (int a = 0; a < 4; a++)
#pragma unroll
    for (int b = 0; b < 4; b++) acc[a][b] = zero;
  for (int kt = 0; kt < HDIM; kt += 64) {
    __syncthreads();
    stage_tile(Ae + kt, HDIM, ldsA, tid);
    stage_tile(Be + kt, HDIM, ldsB, tid);
    __syncthreads();
#pragma unroll
    for (int kk = 0; kk < 2; kk++) {
      bf16x8 af[4], bfr[4];
#pragma unroll
      for (int rt = 0; rt < 4; rt++) {
        int r = wr + rt * 16 + (lane & 15);
        int c = (kk * 4 + (lane >> 4)) ^ (r & 7);
        af[rt] = *(const bf16x8*)(ldsA + r * 64 + c * 8);
      }
#pragma unroll
      for (int ct = 0; ct < 4; ct++) {
        int r = wc + ct * 16 + (lane & 15);
        int c = (kk * 4 + (lane >> 4)) ^ (r & 7);
        bfr[ct] = *(const bf16x8*)(ldsB + r * 64 + c * 8);
      }
#pragma unroll
      for (int rt = 0; rt < 4; rt++)
#pragma unroll
        for (int ct = 0; ct < 4; ct++)
          acc[rt][ct] = __builtin_amdgcn_mfma_f32_16x16x32_bf16(af[rt], bfr[ct], acc[rt][ct], 0, 0, 0);
    }
  }
  int q = lane >> 4, ln = lane & 15;
  float bias[4];
#pragma unroll
  for (int ct = 0; ct < 4; ct++) bias[ct] = b2[e_abs * MDIM + bn * 128 + wc + ct * 16 + ln];
#pragma unroll
  for (int rt = 0; rt < 4; rt++) {
#pragma unroll
    for (int rg = 0; rg < 4; rg++) {
      int row = bm * 128 + wr + rt * 16 + q * 4 + rg;
      int token = s2t[e_abs * CAP + row];
      if (token < 0) continue;
      float g = gate[token];
#pragma unroll
      for (int ct = 0; ct < 4; ct++) {
        int col = bn * 128 + wc + ct * 16 + ln;
        out[(size_t)token * MDIM + col] = (acc[rt][ct][rg] + bias[ct]) * g;
      }
    }
  }
}

// ---------------- zero rows of dropped tokens ----------------
__global__ __launch_bounds__(256) void zerodrop_kernel(
    const float* __restrict__ gate, float* __restrict__ out) {
  int t = blockIdx.x;
  if (gate[t] != 0.f) return;
  float4 z = {0.f, 0.f, 0.f, 0.f};
  ((float4*)(out + (size_t)t * MDIM))[threadIdx.x] = z;
}

extern "C" void kernel_launch(void* const* d_in, const int* in_sizes, int n_in,
                              void* d_out, int out_size, void* d_ws, size_t ws_size,
                              hipStream_t stream) {
  const float* x  = (const float*)d_in[0];
  const float* wg = (const float*)d_in[1];
  const float* w1 = (const float*)d_in[2];
  const float* b1 = (const float*)d_in[3];
  const float* w2 = (const float*)d_in[4];
  const float* b2 = (const float*)d_in[5];
  float* out = (float*)d_out;

  char* ws = (char*)d_ws;
  size_t off = 0;
  auto alloc = [&](size_t n) { char* ptr = ws + off; off += (n + 255) & ~(size_t)255; return ptr; };
  short* W1t  = (short*)alloc((size_t)NEXP * MDIM * HDIM * 2);   // 67 MB [E][H][M]
  short* W2t  = (short*)alloc((size_t)NEXP * MDIM * HDIM * 2);   // 67 MB [E][M][H]
  short* Hh   = (short*)alloc((size_t)EGRP * CAP * HDIM * 2);    // 67 MB (4 experts, full H)
  short* xb   = (short*)alloc((size_t)TOKENS * MDIM * 2);        // 33.5 MB bf16 x
  short* zrow = (short*)alloc((size_t)MDIM * 2);
  int*   idx  = (int*)  alloc(TOKENS * 4);
  float* gate = (float*)alloc(TOKENS * 4);
  int*   s2t  = (int*)  alloc(NEXP * CAP * 4);
  float* mep  = (float*)alloc((TOKENS / 4) * NEXP * 4);
  int*   cnts = (int*)  alloc(NEXP * 4);
  if (ws_size < off) return;

  hipMemsetAsync(s2t, 0xFF, NEXP * CAP * 4, stream);  // -1 sentinels
  hipMemsetAsync(zrow, 0, MDIM * 2, stream);

  gating_kernel<<<TOKENS / 4, 256, 0, stream>>>(x, wg, idx, gate, mep, xb);
  scan_kernel<<<1, 1024, 0, stream>>>(idx, gate, s2t, cnts);
  finalize_kernel<<<1, 256, 0, stream>>>(mep, cnts, out + (size_t)TOKENS * MDIM, TOKENS / 4);
  transpose_cvt_kernel<<<dim3(HDIM / 32, MDIM / 32, NEXP), 256, 0, stream>>>(w1, W1t, MDIM, HDIM);
  transpose_cvt_kernel<<<dim3(MDIM / 32, HDIM / 32, NEXP), 256, 0, stream>>>(w2, W2t, HDIM, MDIM);
  for (int g = 0; g < 2; g++) {
    gemm1_kernel<<<dim3(HDIM / 128, CAP / 128, EGRP), 256, 0, stream>>>(xb, s2t, W1t, b1, Hh, zrow, g * EGRP);
    gemm2_kernel<<<dim3(MDIM / 128, CAP / 128, EGRP), 256, 0, stream>>>(Hh, W2t, b2, s2t, gate, out, g * EGRP);
  }
  zerodrop_kernel<<<TOKENS, 256, 0, stream>>>(gate, out);
}

// Round 3
// 915.594 us; speedup vs baseline: 1.1107x; 1.0196x over previous
//
#include <hip/hip_runtime.h>
#include <hip/hip_bf16.h>

#define TOKENS 16384
#define MDIM   1024
#define HDIM   4096
#define NEXP   8
#define EGRP   4          // experts per GEMM group (2 groups)
#define CAP    2048

typedef __attribute__((ext_vector_type(8))) short bf16x8;  // 8 bf16 = 4 VGPR
typedef __attribute__((ext_vector_type(4))) float f32x4;

__device__ __forceinline__ short f2bf(float x) {
  unsigned u = __float_as_uint(x);
  unsigned r = (u + 0x7fffu + ((u >> 16) & 1u)) >> 16;
  return (short)r;
}

// round bits to bf16 boundary (RNE), result in high 16 bits
__device__ __forceinline__ unsigned bfbits(float x) {
  unsigned u = __float_as_uint(x);
  return u + 0x7fffu + ((u >> 16) & 1u);
}

__device__ __forceinline__ float gelu_f(float x) {
  // jax.nn.gelu approximate=True
  float u = 1.5957691216057308f * (x + 0.044715f * x * x * x);
  float e = __expf(u);
  return x * (1.f - 1.f / (e + 1.f));
}

// ---------------- gating: logits -> softmax -> argmax; also emit bf16 x ----------------
__global__ __launch_bounds__(256) void gating_kernel(
    const float* __restrict__ x, const float* __restrict__ wg,
    int* __restrict__ idx, float* __restrict__ gate,
    float* __restrict__ mepart, short* __restrict__ xb) {
  __shared__ float me_s[NEXP];
  int tid = threadIdx.x, wid = tid >> 6, lane = tid & 63;
  if (tid < NEXP) me_s[tid] = 0.f;
  __syncthreads();
  int t = blockIdx.x * 4 + wid;
  float acc[NEXP];
#pragma unroll
  for (int e = 0; e < NEXP; e++) acc[e] = 0.f;
  const float4* xr = (const float4*)(x + (size_t)t * MDIM);
  short* xbr = xb + (size_t)t * MDIM + lane * 16;
#pragma unroll
  for (int j = 0; j < 4; j++) {
    float4 xv = xr[lane * 4 + j];
    short4 bv; bv.x = f2bf(xv.x); bv.y = f2bf(xv.y); bv.z = f2bf(xv.z); bv.w = f2bf(xv.w);
    ((short4*)(xbr))[j] = bv;
    int base = lane * 16 + j * 4;
    const float* xp = &xv.x;
#pragma unroll
    for (int i = 0; i < 4; i++) {
      float xi = xp[i];
      const float4* wr = (const float4*)(wg + (size_t)(base + i) * NEXP);
      float4 w0 = wr[0], w1 = wr[1];
      acc[0] += xi * w0.x; acc[1] += xi * w0.y; acc[2] += xi * w0.z; acc[3] += xi * w0.w;
      acc[4] += xi * w1.x; acc[5] += xi * w1.y; acc[6] += xi * w1.z; acc[7] += xi * w1.w;
    }
  }
#pragma unroll
  for (int off = 32; off > 0; off >>= 1)
#pragma unroll
    for (int e = 0; e < NEXP; e++) acc[e] += __shfl_xor(acc[e], off, 64);
  if (lane == 0) {
    float mx = acc[0]; int ai = 0;
#pragma unroll
    for (int e = 1; e < NEXP; e++) if (acc[e] > mx) { mx = acc[e]; ai = e; }
    float ex[NEXP]; float se = 0.f;
#pragma unroll
    for (int e = 0; e < NEXP; e++) { ex[e] = __expf(acc[e] - mx); se += ex[e]; }
    float inv = 1.f / se;
#pragma unroll
    for (int e = 0; e < NEXP; e++) atomicAdd(&me_s[e], ex[e] * inv);
    idx[t] = ai;
    gate[t] = inv;
  }
  __syncthreads();
  if (tid < NEXP) mepart[blockIdx.x * NEXP + tid] = me_s[tid];
}

// ---------------- ordered scan: queue positions (2 barriers total) ----------------
__global__ __launch_bounds__(1024) void scan_kernel(
    const int* __restrict__ idx, float* __restrict__ gate,
    int* __restrict__ s2t, int* __restrict__ counts) {
  __shared__ int wcnt[16][NEXP];
  __shared__ int wbase[16][NEXP];
  int tid = threadIdx.x, wid = tid >> 6, lane = tid & 63;
  unsigned long long ltmask = (1ull << lane) - 1ull;
  int myexp[16], myloc[16];
  int cnt[NEXP];
#pragma unroll
  for (int e = 0; e < NEXP; e++) cnt[e] = 0;
  int base_tok = wid * 1024;
#pragma unroll
  for (int p = 0; p < 16; p++) {
    int e = idx[base_tok + p * 64 + lane];
    myexp[p] = e;
    int pos = 0;
#pragma unroll
    for (int e2 = 0; e2 < NEXP; e2++) {
      unsigned long long b = __ballot(e == e2);
      if (e == e2) pos = cnt[e2] + __popcll(b & ltmask);
      cnt[e2] += __popcll(b);            // wave-uniform
    }
    myloc[p] = pos;
  }
  if (lane < NEXP) wcnt[wid][lane] = cnt[lane];
  __syncthreads();
  if (tid < 128) {
    int w = tid >> 3, e = tid & 7;
    int s = 0;
    for (int w2 = 0; w2 < w; w2++) s += wcnt[w2][e];
    wbase[w][e] = s;
  }
  __syncthreads();
#pragma unroll
  for (int p = 0; p < 16; p++) {
    int i = base_tok + p * 64 + lane;
    int e = myexp[p];
    int loc = wbase[wid][e] + myloc[p];
    if (loc < CAP) s2t[e * CAP + loc] = i;
    else           gate[i] = 0.f;
  }
  if (tid < NEXP) {
    int tot = 0;
#pragma unroll
    for (int w = 0; w < 16; w++) tot += wcnt[w][tid];
    counts[tid] = tot;
  }
}

// ---------------- l_aux + exp_counts tail ----------------
__global__ __launch_bounds__(256) void finalize_kernel(
    const float* __restrict__ mepart, const int* __restrict__ counts,
    float* __restrict__ out_tail, int nblocks) {
  __shared__ float red[256];
  __shared__ float me[NEXP];
  int tid = threadIdx.x;
  float s = 0.f;
  int e = tid & 7;
  for (int r = tid >> 3; r < nblocks; r += 32) s += mepart[r * NEXP + e];
  red[tid] = s;
  __syncthreads();
  if (tid < NEXP) {
    float tsum = 0.f;
    for (int i = tid; i < 256; i += 8) tsum += red[i];
    me[tid] = tsum;
  }
  __syncthreads();
  if (tid == 0) {
    float la = 0.f;
    for (int k = 0; k < NEXP; k++)
      la += (me[k] / (float)TOKENS) * ((float)counts[k] / (float)TOKENS);
    out_tail[0] = la * (float)NEXP;
  }
  if (tid < NEXP) out_tail[1 + tid] = (float)counts[tid];
}

// ---------------- fp32 [E][R][C] -> bf16 [E][C][R], 64x64 LDS tiles ----------------
__global__ __launch_bounds__(256) void transpose_cvt_kernel(
    const float* __restrict__ in, short* __restrict__ out, int R, int Cc) {
  __shared__ short tile[64][72];   // pad 72: 8B-aligned b64 reads, <=2-way banks
  int e = blockIdx.z;
  const float* in_e = in + (size_t)e * R * Cc;
  short* out_e = out + (size_t)e * R * Cc;
  int r0 = blockIdx.y * 64, c0 = blockIdx.x * 64;
  int tid = threadIdx.x;
#pragma unroll
  for (int i = 0; i < 4; i++) {
    int linear = tid + 256 * i;          // 0..1023
    int r = linear >> 4;                 // 0..63
    int f4 = linear & 15;                // 0..15
    float4 v = *(const float4*)(in_e + (size_t)(r0 + r) * Cc + c0 + f4 * 4);
    int c = f4 * 4;
    tile[c + 0][r] = f2bf(v.x);
    tile[c + 1][r] = f2bf(v.y);
    tile[c + 2][r] = f2bf(v.z);
    tile[c + 3][r] = f2bf(v.w);
  }
  __syncthreads();
#pragma unroll
  for (int i = 0; i < 4; i++) {
    int linear = tid + 256 * i;
    int c = linear >> 4;
    int s4 = linear & 15;
    short4 s;
    s.x = tile[c][s4 * 4 + 0]; s.y = tile[c][s4 * 4 + 1];
    s.z = tile[c][s4 * 4 + 2]; s.w = tile[c][s4 * 4 + 3];
    *(short4*)(out_e + (size_t)(c0 + c) * R + r0 + s4 * 4) = s;
  }
}

// ---------------- m97-style staging ----------------
__device__ __forceinline__ void stage_tile(const short* __restrict__ g0, int ldk,
                                           short* lds, int tid) {
  int w = tid >> 6, lane = tid & 63;
#pragma unroll
  for (int i = 0; i < 4; i++) {
    int rbase = w * 32 + i * 8;
    int r = rbase + (lane >> 3);
    int c = (lane & 7) ^ (r & 7);
    const short* g = g0 + (size_t)r * ldk + c * 8;
    short* l = lds + rbase * 64;
    __builtin_amdgcn_global_load_lds((const __attribute__((address_space(1))) void*)g,
                                     (__attribute__((address_space(3))) void*)l,
                                     16, 0, 0);
  }
}

// ---------------- GEMM1 (gathered A): xb rows via s2t @ W1t^T -> gelu -> Hh ----------------
// MFMA operands swapped: D[m=H(reg dim)][n=cap(lane dim)] -> thread holds 4
// consecutive H columns at a fixed cap row -> packed 8B stores.
__global__ __launch_bounds__(256) void gemm1_kernel(
    const short* __restrict__ xb, const int* __restrict__ s2t,
    const short* __restrict__ W1t, const float* __restrict__ b1,
    short* __restrict__ Hh, const short* __restrict__ zrow, int eg) {
  __shared__ __align__(16) short ldsA[128 * 64];
  __shared__ __align__(16) short ldsB[128 * 64];
  int bz = blockIdx.z, bm = blockIdx.y, bn = blockIdx.x;
  int e_abs = eg + bz;
  const short* Be = W1t + ((size_t)e_abs * HDIM + (size_t)bn * 128) * MDIM;
  int tid = threadIdx.x, lane = tid & 63, w = tid >> 6;
  const short* aptr[4];
#pragma unroll
  for (int i = 0; i < 4; i++) {
    int rb = w * 32 + i * 8;
    int r = rb + (lane >> 3);
    int tok = s2t[e_abs * CAP + bm * 128 + r];
    const short* basep = (tok >= 0) ? (xb + (size_t)tok * MDIM) : zrow;
    aptr[i] = basep + (((lane & 7) ^ (r & 7)) * 8);
  }
  int wr = (w >> 1) * 64, wc = (w & 1) * 64;
  f32x4 acc[4][4];   // [ct: H tile][rt: cap tile]
  f32x4 zero = {0.f, 0.f, 0.f, 0.f};
#pragma unroll
  for (int a = 0; a < 4; a++)
#pragma unroll
    for (int b = 0; b < 4; b++) acc[a][b] = zero;
  for (int kt = 0; kt < MDIM; kt += 64) {
    __syncthreads();
#pragma unroll
    for (int i = 0; i < 4; i++) {
      short* l = ldsA + (w * 32 + i * 8) * 64;
      __builtin_amdgcn_global_load_lds((const __attribute__((address_space(1))) void*)(aptr[i] + kt),
                                       (__attribute__((address_space(3))) void*)l,
                                       16, 0, 0);
    }
    stage_tile(Be + kt, MDIM, ldsB, tid);
    __syncthreads();
#pragma unroll
    for (int kk = 0; kk < 2; kk++) {
      bf16x8 af[4], bfr[4];
#pragma unroll
      for (int rt = 0; rt < 4; rt++) {
        int r = wr + rt * 16 + (lane & 15);
        int c = (kk * 4 + (lane >> 4)) ^ (r & 7);
        af[rt] = *(const bf16x8*)(ldsA + r * 64 + c * 8);
      }
#pragma unroll
      for (int ct = 0; ct < 4; ct++) {
        int r = wc + ct * 16 + (lane & 15);
        int c = (kk * 4 + (lane >> 4)) ^ (r & 7);
        bfr[ct] = *(const bf16x8*)(ldsB + r * 64 + c * 8);
      }
#pragma unroll
      for (int rt = 0; rt < 4; rt++)
#pragma unroll
        for (int ct = 0; ct < 4; ct++)
          acc[ct][rt] = __builtin_amdgcn_mfma_f32_16x16x32_bf16(bfr[ct], af[rt], acc[ct][rt], 0, 0, 0);
    }
  }
  int q = lane >> 4, ln = lane & 15;
#pragma unroll
  for (int rt = 0; rt < 4; rt++) {
    int caprow = bm * 128 + wr + rt * 16 + ln;
    size_t rowoff = ((size_t)bz * CAP + caprow) * HDIM;
#pragma unroll
    for (int ct = 0; ct < 4; ct++) {
      int colb = bn * 128 + wc + ct * 16 + q * 4;     // 4 consecutive H cols
      float4 bias = *(const float4*)(b1 + (size_t)e_abs * HDIM + colb);
      unsigned u0 = bfbits(gelu_f(acc[ct][rt][0] + bias.x));
      unsigned u1 = bfbits(gelu_f(acc[ct][rt][1] + bias.y));
      unsigned u2 = bfbits(gelu_f(acc[ct][rt][2] + bias.z));
      unsigned u3 = bfbits(gelu_f(acc[ct][rt][3] + bias.w));
      uint2 pk;
      pk.x = __builtin_amdgcn_perm(u1, u0, 0x07060302u);
      pk.y = __builtin_amdgcn_perm(u3, u2, 0x07060302u);
      *(uint2*)(Hh + rowoff + colb) = pk;
    }
  }
}

// ---------------- GEMM2 (full K=H) + fused combine, float4 stores ----------------
__global__ __launch_bounds__(256) void gemm2_kernel(
    const short* __restrict__ Hh, const short* __restrict__ W2t,
    const float* __restrict__ b2, const int* __restrict__ s2t,
    const float* __restrict__ gate, float* __restrict__ out, int eg) {
  __shared__ __align__(16) short ldsA[128 * 64];
  __shared__ __align__(16) short ldsB[128 * 64];
  int bz = blockIdx.z, bm = blockIdx.y, bn = blockIdx.x;
  int e_abs = eg + bz;
  const short* Ae = Hh + ((size_t)bz * CAP + (size_t)bm * 128) * HDIM;
  const short* Be = W2t + ((size_t)e_abs * MDIM + (size_t)bn * 128) * HDIM;
  int tid = threadIdx.x, lane = tid & 63, w = tid >> 6;
  int wr = (w >> 1) * 64, wc = (w & 1) * 64;
  f32x4 acc[4][4];   // [ct: M tile][rt: cap tile]
  f32x4 zero = {0.f, 0.f, 0.f, 0.f};
#pragma unroll
  for (int a = 0; a < 4; a++)
#pragma unroll
    for (int b = 0; b < 4; b++) acc[a][b] = zero;
  for (int kt = 0; kt < HDIM; kt += 64) {
    __syncthreads();
    stage_tile(Ae + kt, HDIM, ldsA, tid);
    stage_tile(Be + kt, HDIM, ldsB, tid);
    __syncthreads();
#pragma unroll
    for (int kk = 0; kk < 2; kk++) {
      bf16x8 af[4], bfr[4];
#pragma unroll
      for (int rt = 0; rt < 4; rt++) {
        int r = wr + rt * 16 + (lane & 15);
        int c = (kk * 4 + (lane >> 4)) ^ (r & 7);
        af[rt] = *(const bf16x8*)(ldsA + r * 64 + c * 8);
      }
#pragma unroll
      for (int ct = 0; ct < 4; ct++) {
        int r = wc + ct * 16 + (lane & 15);
        int c = (kk * 4 + (lane >> 4)) ^ (r & 7);
        bfr[ct] = *(const bf16x8*)(ldsB + r * 64 + c * 8);
      }
#pragma unroll
      for (int rt = 0; rt < 4; rt++)
#pragma unroll
        for (int ct = 0; ct < 4; ct++)
          acc[ct][rt] = __builtin_amdgcn_mfma_f32_16x16x32_bf16(bfr[ct], af[rt], acc[ct][rt], 0, 0, 0);
    }
  }
  int q = lane >> 4, ln = lane & 15;
#pragma unroll
  for (int rt = 0; rt < 4; rt++) {
    int caprow = bm * 128 + wr + rt * 16 + ln;
    int token = s2t[e_abs * CAP + caprow];
    if (token < 0) continue;
    float g = gate[token];
    float* orow = out + (size_t)token * MDIM;
#pragma unroll
    for (int ct = 0; ct < 4; ct++) {
      int colb = bn * 128 + wc + ct * 16 + q * 4;     // 4 consecutive M cols
      float4 bias = *(const float4*)(b2 + (size_t)e_abs * MDIM + colb);
      float4 v;
      v.x = (acc[ct][rt][0] + bias.x) * g;
      v.y = (acc[ct][rt][1] + bias.y) * g;
      v.z = (acc[ct][rt][2] + bias.z) * g;
      v.w = (acc[ct][rt][3] + bias.w) * g;
      *(float4*)(orow + colb) = v;
    }
  }
}

// ---------------- zero rows of dropped tokens ----------------
__global__ __launch_bounds__(256) void zerodrop_kernel(
    const float* __restrict__ gate, float* __restrict__ out) {
  int t = blockIdx.x;
  if (gate[t] != 0.f) return;
  float4 z = {0.f, 0.f, 0.f, 0.f};
  ((float4*)(out + (size_t)t * MDIM))[threadIdx.x] = z;
}

extern "C" void kernel_launch(void* const* d_in, const int* in_sizes, int n_in,
                              void* d_out, int out_size, void* d_ws, size_t ws_size,
                              hipStream_t stream) {
  const float* x  = (const float*)d_in[0];
  const float* wg = (const float*)d_in[1];
  const float* w1 = (const float*)d_in[2];
  const float* b1 = (const float*)d_in[3];
  const float* w2 = (const float*)d_in[4];
  const float* b2 = (const float*)d_in[5];
  float* out = (float*)d_out;

  char* ws = (char*)d_ws;
  size_t off = 0;
  auto alloc = [&](size_t n) { char* ptr = ws + off; off += (n + 255) & ~(size_t)255; return ptr; };
  short* W1t  = (short*)alloc((size_t)NEXP * MDIM * HDIM * 2);   // 67 MB [E][H][M]
  short* W2t  = (short*)alloc((size_t)NEXP * MDIM * HDIM * 2);   // 67 MB [E][M][H]
  short* Hh   = (short*)alloc((size_t)EGRP * CAP * HDIM * 2);    // 67 MB (4 experts, full H)
  short* xb   = (short*)alloc((size_t)TOKENS * MDIM * 2);        // 33.5 MB bf16 x
  short* zrow = (short*)alloc((size_t)MDIM * 2);
  int*   idx  = (int*)  alloc(TOKENS * 4);
  float* gate = (float*)alloc(TOKENS * 4);
  int*   s2t  = (int*)  alloc(NEXP * CAP * 4);
  float* mep  = (float*)alloc((TOKENS / 4) * NEXP * 4);
  int*   cnts = (int*)  alloc(NEXP * 4);
  if (ws_size < off) return;

  hipMemsetAsync(s2t, 0xFF, NEXP * CAP * 4, stream);  // -1 sentinels
  hipMemsetAsync(zrow, 0, MDIM * 2, stream);

  gating_kernel<<<TOKENS / 4, 256, 0, stream>>>(x, wg, idx, gate, mep, xb);
  scan_kernel<<<1, 1024, 0, stream>>>(idx, gate, s2t, cnts);
  finalize_kernel<<<1, 256, 0, stream>>>(mep, cnts, out + (size_t)TOKENS * MDIM, TOKENS / 4);
  transpose_cvt_kernel<<<dim3(HDIM / 64, MDIM / 64, NEXP), 256, 0, stream>>>(w1, W1t, MDIM, HDIM);
  transpose_cvt_kernel<<<dim3(MDIM / 64, HDIM / 64, NEXP), 256, 0, stream>>>(w2, W2t, HDIM, MDIM);
  for (int g = 0; g < 2; g++) {
    gemm1_kernel<<<dim3(HDIM / 128, CAP / 128, EGRP), 256, 0, stream>>>(xb, s2t, W1t, b1, Hh, zrow, g * EGRP);
    gemm2_kernel<<<dim3(MDIM / 128, CAP / 128, EGRP), 256, 0, stream>>>(Hh, W2t, b2, s2t, gate, out, g * EGRP);
  }
  zerodrop_kernel<<<TOKENS, 256, 0, stream>>>(gate, out);
}